// Round 6
// baseline (894.078 us; speedup 1.0000x reference)
//
#include <hip/hip_runtime.h>
#include <hip/hip_fp16.h>
#include <math.h>

typedef _Float16 half8 __attribute__((ext_vector_type(8)));
typedef __fp16 fp16x2 __attribute__((ext_vector_type(2)));
typedef float f32x4 __attribute__((ext_vector_type(4)));

#define BATCH 1024
#define IN_DIM 4096
#define HV 8192
#define NTAP 40          // 39 gates -> degree-39 polynomial -> 40 taps

#define BM 128
#define BN 128
#define BK 32
#define BKP 36           // padded LDS row stride (144 B -> bank shift 4/row, <=2-way)

// pack 8 f32 -> 8 f16 (RTZ), 4 VALU instrs
static __device__ __forceinline__ half8 pk8(f32x4 a, f32x4 b) {
    union { fp16x2 p[4]; half8 h; } u;
    u.p[0] = __builtin_amdgcn_cvt_pkrtz(a.x, a.y);
    u.p[1] = __builtin_amdgcn_cvt_pkrtz(a.z, a.w);
    u.p[2] = __builtin_amdgcn_cvt_pkrtz(b.x, b.y);
    u.p[3] = __builtin_amdgcn_cvt_pkrtz(b.z, b.w);
    return u.h;
}

// ---------------- GEMM: out[m*HV + n] = sum_k x[m][k] * W[n][k] ----------------
// Explicit register staging: float4 global load -> ds_write_b128; f32 tiles in LDS
// (padded rows); f32->f16 pack at fragment read; f16 MFMA. Stores guarded by out_n.
__global__ __launch_bounds__(256) void gemm_f32in(
        const float* __restrict__ A,   // x  [BATCH][IN_DIM]
        const float* __restrict__ B,   // W  [HV][IN_DIM]
        float* __restrict__ out,       // [out_n] floats = classical [BATCH][HV]
        long out_n) {
    __shared__ __align__(16) float lgA[BM * BKP];   // 18 KB
    __shared__ __align__(16) float lgB[BN * BKP];   // 18 KB

    const int tid  = threadIdx.x;
    const int lane = tid & 63;
    const int wave = tid >> 6;
    const int wm = wave & 1, wn = wave >> 1;
    const int q = lane >> 4, r = lane & 15;
    const int bm = blockIdx.y * BM;
    const int bn = blockIdx.x * BN;

    // staging: lane -> row group rg = lane>>3 (8 rows/instr), col (lane&7)*4 floats
    const int rg = lane >> 3;
    const int cg = (lane & 7) * 4;
    const float* gA = A + (size_t)(bm + wave * 32 + rg) * IN_DIM + cg;
    const float* gB = B + (size_t)(bn + wave * 32 + rg) * IN_DIM + cg;
    float* lA = &lgA[(wave * 32 + rg) * BKP + cg];
    float* lB = &lgB[(wave * 32 + rg) * BKP + cg];

    f32x4 acc[4][4] = {};

    for (int k0 = 0; k0 < IN_DIM; k0 += BK) {
        float4 va[4], vb[4];
        #pragma unroll
        for (int i = 0; i < 4; i++) {
            va[i] = *(const float4*)(gA + k0 + (size_t)(8 * i) * IN_DIM);
            vb[i] = *(const float4*)(gB + k0 + (size_t)(8 * i) * IN_DIM);
        }
        __syncthreads();   // previous iteration's fragment reads complete
        #pragma unroll
        for (int i = 0; i < 4; i++) {
            *(float4*)(lA + 8 * i * BKP) = va[i];
            *(float4*)(lB + 8 * i * BKP) = vb[i];
        }
        __syncthreads();   // tile staged

        half8 af[4], bf[4];
        #pragma unroll
        for (int i = 0; i < 4; i++) {
            const float* p = &lgA[(wm * 64 + i * 16 + r) * BKP + q * 8];
            af[i] = pk8(*(const f32x4*)p, *(const f32x4*)(p + 4));
        }
        #pragma unroll
        for (int j = 0; j < 4; j++) {
            const float* p = &lgB[(wn * 64 + j * 16 + r) * BKP + q * 8];
            bf[j] = pk8(*(const f32x4*)p, *(const f32x4*)(p + 4));
        }

        #pragma unroll
        for (int i = 0; i < 4; i++)
            #pragma unroll
            for (int j = 0; j < 4; j++)
                acc[i][j] = __builtin_amdgcn_mfma_f32_16x16x32_f16(af[i], bf[j], acc[i][j], 0, 0, 0);
    }

    // C/D layout: col = lane&15, row = (lane>>4)*4 + reg.  Guarded stores.
    #pragma unroll
    for (int i = 0; i < 4; i++) {
        const int row = bm + wm * 64 + i * 16 + q * 4;
        #pragma unroll
        for (int j = 0; j < 4; j++) {
            const int col = bn + wn * 64 + j * 16 + r;
            #pragma unroll
            for (int reg = 0; reg < 4; reg++) {
                long idx = (long)(row + reg) * HV + col;
                if (idx < out_n) out[idx] = acc[i][j][reg];
            }
        }
    }
}

// ---------------- fused normalize + real-part 40-tap circular conv, in place ----------------
// Block b: row b of classical (8192 floats) -> Re(amps) row b.
// Re(amp_i) = (1/||v||) * sum_k Re(c_k) * cls[(i-k) mod HV]
__global__ __launch_bounds__(256) void norm_conv(float* __restrict__ out,
                                                 const float* __restrict__ qp,
                                                 long out_n) {
    __shared__ __align__(16) float ldsv[HV + 48];   // ldsv[p] = v[(p-40) mod HV]
    __shared__ float scr[NTAP];
    __shared__ float red[4];

    const int b = blockIdx.x;
    if ((long)(b + 1) * HV > out_n) return;         // uniform per block

    const int tid = threadIdx.x;
    const int lane = tid & 63;
    const int wave = tid >> 6;
    float* rowp = out + (size_t)b * HV;
    const float4* row4 = (const float4*)rowp;
    float4* l4 = (float4*)ldsv;

    // load row into LDS shifted by NTAP, accumulate sum of squares
    float ss = 0.f;
    #pragma unroll
    for (int it = 0; it < 8; it++) {
        int j = it * 256 + tid;                 // float4 index 0..2047
        float4 v = row4[j];
        ss += v.x * v.x + v.y * v.y + v.z * v.z + v.w * v.w;
        l4[10 + j] = v;                         // NTAP/4 = 10
    }
    if (tid < NTAP) ldsv[tid] = rowp[HV - NTAP + tid];   // wrap region

    #pragma unroll
    for (int off = 32; off > 0; off >>= 1) ss += __shfl_down(ss, off, 64);
    if (lane == 0) red[wave] = ss;

    // wave 0: lane-parallel polynomial product  P <- c*P + i*s*Z*P  over 39 gates
    if (wave == 0) {
        float qv = (lane < 39) ? qp[lane] : 0.f;
        float pr = (lane == 0) ? 1.f : 0.f;
        float pim = 0.f;
        for (int t = 0; t < 39; t++) {
            float a = __shfl(qv, t, 64) * 0.5f;
            float c = cosf(a), s = sinf(a);
            float ur = __shfl_up(pr, 1, 64);
            float ui = __shfl_up(pim, 1, 64);
            if (lane == 0) { ur = 0.f; ui = 0.f; }
            float nr = c * pr - s * ui;
            float ni = c * pim + s * ur;
            pr = nr; pim = ni;
        }
        if (lane < NTAP) scr[lane] = pr;        // only real parts needed
    }
    __syncthreads();

    const float inv = 1.0f / sqrtf(red[0] + red[1] + red[2] + red[3]);
    float rc[NTAP];
    #pragma unroll
    for (int k = 0; k < NTAP; k++) rc[k] = scr[k] * inv;

    float4* out4 = (float4*)rowp;
    #pragma unroll
    for (int it = 0; it < 8; it++) {
        const int i0 = (it * 256 + tid) * 4;    // output element base
        float w[48];
        #pragma unroll
        for (int t = 0; t < 12; t++) ((float4*)w)[t] = l4[(i0 >> 2) + t];

        float ar[4] = {0.f, 0.f, 0.f, 0.f};
        #pragma unroll
        for (int k = 0; k < NTAP; k++) {
            const float c0 = rc[k];
            #pragma unroll
            for (int o = 0; o < 4; o++)
                ar[o] += c0 * w[o + NTAP - k];  // v[(i0+o-k) mod HV]
        }
        out4[i0 >> 2] = make_float4(ar[0], ar[1], ar[2], ar[3]);
    }
}

// ---------------- launch: zero workspace usage, out_size-guarded ----------------
extern "C" void kernel_launch(void* const* d_in, const int* in_sizes, int n_in,
                              void* d_out, int out_size, void* d_ws, size_t ws_size,
                              hipStream_t stream) {
    const float* x  = (const float*)d_in[0];   // [1024][4096]
    const float* W  = (const float*)d_in[1];   // [8192][4096]
    const float* qp = (const float*)d_in[2];   // [39]
    float* out = (float*)d_out;                // [1024][8192] floats (Re of amps)
    long out_n = (long)out_size;

    dim3 grid(HV / BN, BATCH / BM);            // (64, 8)
    gemm_f32in<<<grid, 256, 0, stream>>>(x, W, out, out_n);
    norm_conv<<<BATCH, 256, 0, stream>>>(out, qp, out_n);
}

// Round 7
// 342.951 us; speedup vs baseline: 2.6070x; 2.6070x over previous
//
#include <hip/hip_runtime.h>
#include <hip/hip_fp16.h>
#include <math.h>

typedef _Float16 half8 __attribute__((ext_vector_type(8)));
typedef __fp16 fp16x2 __attribute__((ext_vector_type(2)));
typedef float f32x4 __attribute__((ext_vector_type(4)));

#define BATCH 1024
#define IN_DIM 4096
#define HV 8192
#define NTAP 40          // 39 gates -> degree-39 polynomial -> 40 taps

#define BM 128
#define BN 128
#define BK 32
#define BKP 36           // f32 fallback LDS row stride

#define GLD16(g, l) __builtin_amdgcn_global_load_lds(                          \
    (const __attribute__((address_space(1))) void*)(g),                        \
    (__attribute__((address_space(3))) void*)(l), 16, 0, 0)

// pack 8 f32 -> 8 f16 (RTZ), 4 VALU instrs (fallback path only)
static __device__ __forceinline__ half8 pk8(f32x4 a, f32x4 b) {
    union { fp16x2 p[4]; half8 h; } u;
    u.p[0] = __builtin_amdgcn_cvt_pkrtz(a.x, a.y);
    u.p[1] = __builtin_amdgcn_cvt_pkrtz(a.z, a.w);
    u.p[2] = __builtin_amdgcn_cvt_pkrtz(b.x, b.y);
    u.p[3] = __builtin_amdgcn_cvt_pkrtz(b.z, b.w);
    return u.h;
}

// ---------------- f32 -> f16 conversion (RNE) ----------------
typedef _Float16 half4v __attribute__((ext_vector_type(4)));
__global__ __launch_bounds__(256) void cvt_f32_f16(const float4* __restrict__ src,
                                                   half4v* __restrict__ dst, int n4) {
    int i = blockIdx.x * 256 + threadIdx.x;
    if (i < n4) {
        float4 v = src[i];
        half4v h;
        h.x = (_Float16)v.x; h.y = (_Float16)v.y;
        h.z = (_Float16)v.z; h.w = (_Float16)v.w;
        dst[i] = h;
    }
}

// ---------------- primary GEMM (m97 structure): f16 inputs, GLD16 staging ----------------
// out[m*HV + n] = sum_k A[m][k] * B[n][k]
__global__ __launch_bounds__(256) void gemm_f16(
        const _Float16* __restrict__ A,   // [BATCH][IN_DIM] f16
        const _Float16* __restrict__ B,   // [HV][IN_DIM]   f16
        float* __restrict__ out,          // classical [BATCH][HV]
        long out_n) {
    __shared__ __align__(16) _Float16 lgA[BM * BK];   // 8 KB
    __shared__ __align__(16) _Float16 lgB[BN * BK];   // 8 KB

    const int tid  = threadIdx.x;
    const int lane = tid & 63;
    const int wave = tid >> 6;
    const int wm = wave & 1, wn = wave >> 1;
    const int q = lane >> 4, r = lane & 15;
    const int bm = blockIdx.y * BM;
    const int bn = blockIdx.x * BN;

    // staging: wave w covers rows [w*32, w*32+32); lane -> row w*32+(lane>>2), col (lane&3)*8
    // LDS dest = wave-uniform base + lane*16 B  (matches row*BK+col row-major layout)
    const int srow = wave * 32 + (lane >> 2);
    const int scol = (lane & 3) * 8;
    const _Float16* gA = A + (size_t)(bm + srow) * IN_DIM + scol;
    const _Float16* gB = B + (size_t)(bn + srow) * IN_DIM + scol;
    _Float16* lA = &lgA[(wave * 32) * BK];
    _Float16* lB = &lgB[(wave * 32) * BK];

    f32x4 acc[4][4] = {};

    for (int k0 = 0; k0 < IN_DIM; k0 += BK) {
        GLD16(gA + k0,                       lA);
        GLD16(gA + k0 + (size_t)16 * IN_DIM, lA + 16 * BK);
        GLD16(gB + k0,                       lB);
        GLD16(gB + k0 + (size_t)16 * IN_DIM, lB + 16 * BK);
        __syncthreads();   // drains vmcnt: tile staged

        half8 af[4], bf[4];
        #pragma unroll
        for (int i = 0; i < 4; i++)
            af[i] = *(const half8*)&lgA[(wm * 64 + i * 16 + r) * BK + q * 8];
        #pragma unroll
        for (int j = 0; j < 4; j++)
            bf[j] = *(const half8*)&lgB[(wn * 64 + j * 16 + r) * BK + q * 8];

        #pragma unroll
        for (int i = 0; i < 4; i++)
            #pragma unroll
            for (int j = 0; j < 4; j++)
                acc[i][j] = __builtin_amdgcn_mfma_f32_16x16x32_f16(af[i], bf[j], acc[i][j], 0, 0, 0);
        __syncthreads();   // all fragment reads done before next staging overwrites
    }

    // C/D layout: col = lane&15, row = (lane>>4)*4 + reg.  Guarded stores.
    #pragma unroll
    for (int i = 0; i < 4; i++) {
        const int row = bm + wm * 64 + i * 16 + q * 4;
        #pragma unroll
        for (int j = 0; j < 4; j++) {
            const int col = bn + wn * 64 + j * 16 + r;
            #pragma unroll
            for (int reg = 0; reg < 4; reg++) {
                long idx = (long)(row + reg) * HV + col;
                if (idx < out_n) out[idx] = acc[i][j][reg];
            }
        }
    }
}

// ---------------- fallback GEMM: f32 inputs, register staging (R6, proven) ----------------
__global__ __launch_bounds__(256) void gemm_f32in(
        const float* __restrict__ A, const float* __restrict__ B,
        float* __restrict__ out, long out_n) {
    __shared__ __align__(16) float lgA[BM * BKP];
    __shared__ __align__(16) float lgB[BN * BKP];

    const int tid  = threadIdx.x;
    const int lane = tid & 63;
    const int wave = tid >> 6;
    const int wm = wave & 1, wn = wave >> 1;
    const int q = lane >> 4, r = lane & 15;
    const int bm = blockIdx.y * BM;
    const int bn = blockIdx.x * BN;

    const int rg = lane >> 3;
    const int cg = (lane & 7) * 4;
    const float* gA = A + (size_t)(bm + wave * 32 + rg) * IN_DIM + cg;
    const float* gB = B + (size_t)(bn + wave * 32 + rg) * IN_DIM + cg;
    float* lA = &lgA[(wave * 32 + rg) * BKP + cg];
    float* lB = &lgB[(wave * 32 + rg) * BKP + cg];

    f32x4 acc[4][4] = {};

    for (int k0 = 0; k0 < IN_DIM; k0 += BK) {
        float4 va[4], vb[4];
        #pragma unroll
        for (int i = 0; i < 4; i++) {
            va[i] = *(const float4*)(gA + k0 + (size_t)(8 * i) * IN_DIM);
            vb[i] = *(const float4*)(gB + k0 + (size_t)(8 * i) * IN_DIM);
        }
        __syncthreads();
        #pragma unroll
        for (int i = 0; i < 4; i++) {
            *(float4*)(lA + 8 * i * BKP) = va[i];
            *(float4*)(lB + 8 * i * BKP) = vb[i];
        }
        __syncthreads();

        half8 af[4], bf[4];
        #pragma unroll
        for (int i = 0; i < 4; i++) {
            const float* p = &lgA[(wm * 64 + i * 16 + r) * BKP + q * 8];
            af[i] = pk8(*(const f32x4*)p, *(const f32x4*)(p + 4));
        }
        #pragma unroll
        for (int j = 0; j < 4; j++) {
            const float* p = &lgB[(wn * 64 + j * 16 + r) * BKP + q * 8];
            bf[j] = pk8(*(const f32x4*)p, *(const f32x4*)(p + 4));
        }

        #pragma unroll
        for (int i = 0; i < 4; i++)
            #pragma unroll
            for (int j = 0; j < 4; j++)
                acc[i][j] = __builtin_amdgcn_mfma_f32_16x16x32_f16(af[i], bf[j], acc[i][j], 0, 0, 0);
    }

    #pragma unroll
    for (int i = 0; i < 4; i++) {
        const int row = bm + wm * 64 + i * 16 + q * 4;
        #pragma unroll
        for (int j = 0; j < 4; j++) {
            const int col = bn + wn * 64 + j * 16 + r;
            #pragma unroll
            for (int reg = 0; reg < 4; reg++) {
                long idx = (long)(row + reg) * HV + col;
                if (idx < out_n) out[idx] = acc[i][j][reg];
            }
        }
    }
}

// ---------------- fused normalize + real-part 40-tap circular conv, in place ----------------
__global__ __launch_bounds__(256) void norm_conv(float* __restrict__ out,
                                                 const float* __restrict__ qp,
                                                 long out_n) {
    __shared__ __align__(16) float ldsv[HV + 48];
    __shared__ float scr[NTAP];
    __shared__ float red[4];

    const int b = blockIdx.x;
    if ((long)(b + 1) * HV > out_n) return;

    const int tid = threadIdx.x;
    const int lane = tid & 63;
    const int wave = tid >> 6;
    float* rowp = out + (size_t)b * HV;
    const float4* row4 = (const float4*)rowp;
    float4* l4 = (float4*)ldsv;

    float ss = 0.f;
    #pragma unroll
    for (int it = 0; it < 8; it++) {
        int j = it * 256 + tid;
        float4 v = row4[j];
        ss += v.x * v.x + v.y * v.y + v.z * v.z + v.w * v.w;
        l4[10 + j] = v;                         // NTAP/4 = 10
    }
    if (tid < NTAP) ldsv[tid] = rowp[HV - NTAP + tid];

    #pragma unroll
    for (int off = 32; off > 0; off >>= 1) ss += __shfl_down(ss, off, 64);
    if (lane == 0) red[wave] = ss;

    if (wave == 0) {
        float qv = (lane < 39) ? qp[lane] : 0.f;
        float pr = (lane == 0) ? 1.f : 0.f;
        float pim = 0.f;
        for (int t = 0; t < 39; t++) {
            float a = __shfl(qv, t, 64) * 0.5f;
            float c = cosf(a), s = sinf(a);
            float ur = __shfl_up(pr, 1, 64);
            float ui = __shfl_up(pim, 1, 64);
            if (lane == 0) { ur = 0.f; ui = 0.f; }
            float nr = c * pr - s * ui;
            float ni = c * pim + s * ur;
            pr = nr; pim = ni;
        }
        if (lane < NTAP) scr[lane] = pr;        // only real parts needed
    }
    __syncthreads();

    const float inv = 1.0f / sqrtf(red[0] + red[1] + red[2] + red[3]);
    float rc[NTAP];
    #pragma unroll
    for (int k = 0; k < NTAP; k++) rc[k] = scr[k] * inv;

    float4* out4 = (float4*)rowp;
    #pragma unroll
    for (int it = 0; it < 8; it++) {
        const int i0 = (it * 256 + tid) * 4;
        float w[48];
        #pragma unroll
        for (int t = 0; t < 12; t++) ((float4*)w)[t] = l4[(i0 >> 2) + t];

        float ar[4] = {0.f, 0.f, 0.f, 0.f};
        #pragma unroll
        for (int k = 0; k < NTAP; k++) {
            const float c0 = rc[k];
            #pragma unroll
            for (int o = 0; o < 4; o++)
                ar[o] += c0 * w[o + NTAP - k];
        }
        out4[i0 >> 2] = make_float4(ar[0], ar[1], ar[2], ar[3]);
    }
}

// ---------------- launch ----------------
extern "C" void kernel_launch(void* const* d_in, const int* in_sizes, int n_in,
                              void* d_out, int out_size, void* d_ws, size_t ws_size,
                              hipStream_t stream) {
    const float* x  = (const float*)d_in[0];   // [1024][4096]
    const float* W  = (const float*)d_in[1];   // [8192][4096]
    const float* qp = (const float*)d_in[2];   // [39]
    float* out = (float*)d_out;                // [1024][8192] floats (Re of amps)
    long out_n = (long)out_size;

    const size_t need = (size_t)BATCH * IN_DIM * 2 + (size_t)HV * IN_DIM * 2;  // 72 MB
    dim3 grid(HV / BN, BATCH / BM);            // (64, 8)

    if (ws_size >= need) {
        _Float16* xh = (_Float16*)d_ws;
        _Float16* wh = xh + (size_t)BATCH * IN_DIM;
        int n4x = BATCH * IN_DIM / 4;          // 1,048,576
        int n4w = HV * IN_DIM / 4;             // 8,388,608
        cvt_f32_f16<<<n4x / 256, 256, 0, stream>>>((const float4*)x, (half4v*)xh, n4x);
        cvt_f32_f16<<<n4w / 256, 256, 0, stream>>>((const float4*)W, (half4v*)wh, n4w);
        gemm_f16<<<grid, 256, 0, stream>>>(xh, wh, out, out_n);
    } else {
        gemm_f32in<<<grid, 256, 0, stream>>>(x, W, out, out_n);
    }
    norm_conv<<<BATCH, 256, 0, stream>>>(out, qp, out_n);
}